// Round 7
// baseline (226.246 us; speedup 1.0000x reference)
//
#include <hip/hip_runtime.h>
#include <hip/hip_bf16.h>

#define DPROJ 1024

typedef float  f32x4  __attribute__((ext_vector_type(4)));
typedef short  bf16x8 __attribute__((ext_vector_type(8)));

__device__ __forceinline__ unsigned pk2(float a, float b) {
    __hip_bfloat162 h = __float22bfloat162_rn(make_float2(a, b));
    unsigned r; __builtin_memcpy(&r, &h, 4); return r;
}

// async global->LDS, 16B per lane. LDS dest = wave-uniform base + lane*16;
// global src is per-lane. With k-major staging the 64 lanes' sources are one
// CONTIGUOUS 1KB block (r6 layout was stride-2KB -> 4x sector over-fetch).
__device__ __forceinline__ void gll16(const void* g, void* l) {
    __builtin_amdgcn_global_load_lds(
        (const __attribute__((address_space(1))) void*)g,
        (__attribute__((address_space(3))) void*)l, 16, 0, 0);
}

// pb layout (k-major): element (col,k) of table z at pb_z[((k>>3)*1024 + col)*8 + (k&7)]
// chunk counts (16B units): pb0 131072, pb1 32768, pb2 8192, pb3 4096 (kg 2,3 zero)
// ec layout (k-major, pow2-padded rows): cluster z rows padded to P2={2048,2048,16384,8192};
// chunk (kg,r) of z at ec[(EB_z + kg*P2_z + r)*8]; EB = {0,262144,327680,458752}.
// Rows r>=cnt[z] are never read (k_gemm clamps); z=3 kg 2,3 are written zero.

// ---------------- pass 1: classify + proj->bf16 k-major convert -------------
__global__ __launch_bounds__(256) void k_prep(
    const int* __restrict__ inp, int n,
    int* __restrict__ cnt, int* __restrict__ lists,
    const float* __restrict__ p0, const float* __restrict__ p1,
    const float* __restrict__ p2, const float* __restrict__ p3,
    short* __restrict__ pb0, short* __restrict__ pb1,
    short* __restrict__ pb2, short* __restrict__ pb3)
{
    const int tid = threadIdx.x;
    const int b   = blockIdx.x;
    const int CB  = (n + 255) >> 8;
    if (b < CB) {
        const int t = b * 256 + tid;
        int c = -1, l = 0;
        if (t < n) {
            const int x = inp[t];
            c = (x >= 20000) + (x >= 40000) + (x >= 200000);
            l = x - ((c == 0) ? 0 : (c == 1) ? 20000 : (c == 2) ? 40000 : 200000);
        }
        const int lane = tid & 63;
        int pos = 0;
        #pragma unroll
        for (int cc = 0; cc < 4; ++cc) {
            const unsigned long long mk = __ballot(c == cc);
            if (c == cc) {
                const int lead = __ffsll(mk) - 1;
                int base = 0;
                if (lane == lead) base = atomicAdd(&cnt[cc], (int)__popcll(mk));
                base = __shfl(base, lead);
                pos  = base + (int)__popcll(mk & ((1ull << lane) - 1ull));
            }
        }
        if (t < n) lists[c * n + pos] = (int)(((unsigned)t << 18) | (unsigned)l);
    } else {
        // output-linear chunk id: writes coalesced; reads 32B strided (cheap)
        const int g = (b - CB) * 256 + tid;        // 0..176127
        const float* src; short* dst; int o, K;
        if      (g < 131072) { src = p0; dst = pb0; o = g;          K = 1024; }
        else if (g < 163840) { src = p1; dst = pb1; o = g - 131072; K = 256;  }
        else if (g < 172032) { src = p2; dst = pb2; o = g - 163840; K = 64;   }
        else if (g < 176128) { src = p3; dst = pb3; o = g - 172032; K = 16;   }
        else return;
        const int c = o >> 10, col = o & 1023;
        uint4 q = (uint4){0u, 0u, 0u, 0u};
        if (c * 8 < K) {
            const float* s = src + (size_t)col * K + c * 8;
            const float4 a = *(const float4*)s;
            const float4 d = *(const float4*)(s + 4);
            q.x = pk2(a.x, a.y); q.y = pk2(a.z, a.w);
            q.z = pk2(d.x, d.y); q.w = pk2(d.z, d.w);
        }
        *(uint4*)(dst + (size_t)o * 8) = q;
    }
}

// ---------------- pass 2: gather used E rows -> compact k-major bf16 --------
// One 16B chunk per thread, 491520 chunks total. Writes fully coalesced
// (chunk id == output position); reads are the inherent 32B row-gather.
__global__ __launch_bounds__(256) void k_egather(
    const int* __restrict__ cnt, const int* __restrict__ lists, int n,
    const float* __restrict__ e0, const float* __restrict__ e1,
    const float* __restrict__ e2, const float* __restrict__ e3,
    short* __restrict__ ec)
{
    const int i = blockIdx.x * 256 + threadIdx.x;     // 0..491519
    int z, kg, r, Kr; const float* emb;
    if (i < 262144)      { z = 0; kg = i >> 11;  r = i & 2047;  emb = e0; Kr = 1024; }
    else if (i < 327680) { const int t = i - 262144; z = 1; kg = t >> 11; r = t & 2047;  emb = e1; Kr = 256; }
    else if (i < 458752) { const int t = i - 327680; z = 2; kg = t >> 14; r = t & 16383; emb = e2; Kr = 64;  }
    else                 { const int t = i - 458752; z = 3; kg = t >> 13; r = t & 8191;  emb = e3; Kr = 16;  }
    if (r >= cnt[z]) return;                           // never read (row clamp)
    uint4 q = (uint4){0u, 0u, 0u, 0u};
    const int k = kg * 8;
    if (k < Kr) {                                      // z=3 kg 2,3 -> zeros
        const int loc = lists[z * n + r] & 0x3FFFF;
        const float* src = emb + (size_t)loc * Kr + k;
        const float4 a = *(const float4*)src;
        const float4 d = *(const float4*)(src + 4);
        q.x = pk2(a.x, a.y); q.y = pk2(a.z, a.w);
        q.z = pk2(d.x, d.y); q.w = pk2(d.z, d.w);
    }
    *(uint4*)(ec + (size_t)i * 8) = q;
}

// ---------------- pass 3: square-wave-tile pipelined bf16-MFMA GEMM ---------
// r6-verified sync (per K-step):
//   issue next loads -> s_waitcnt vmcnt(5) -> s_barrier   (RAW: cur complete)
//   ds_read cur + MFMA
//   s_waitcnt lgkmcnt(0) -> s_barrier                     (WAR: reads done)
// r7 change: ONLY the global staging addresses (k-major pb/ec -> contiguous
// 1KB per gll16, sector-exact). LDS image, ds_read, MFMA, epilogue unchanged.
// launch_bounds(256,2): no spills (scratch ops would corrupt vmcnt counting).
__global__ __launch_bounds__(256, 2) void k_gemm(
    const int* __restrict__ cnt, const int* __restrict__ lists, int n,
    const short* __restrict__ ec,
    const short* __restrict__ pb0, const short* __restrict__ pb1,
    const short* __restrict__ pb2, const short* __restrict__ pb3,
    float* __restrict__ out)
{
    const int c0 = cnt[0], c1 = cnt[1], c2 = cnt[2], c3 = cnt[3];
    const int T0 = (c0 + 63) >> 6, T1 = (c1 + 63) >> 6;
    const int T2 = (c2 + 63) >> 6, T3 = (c3 + 63) >> 6;
    const int xb = (int)blockIdx.x & 3;
    const int gy = (int)blockIdx.x >> 2;
    if (gy >= T0 + T1 + T2 + T3) return;

    int z, yb;
    if      (gy < T0)           { z = 0; yb = gy; }
    else if (gy < T0 + T1)      { z = 1; yb = gy - T0; }
    else if (gy < T0 + T1 + T2) { z = 2; yb = gy - T0 - T1; }
    else                        { z = 3; yb = gy - T0 - T1 - T2; }

    const int count = (z == 0) ? c0 : (z == 1) ? c1 : (z == 2) ? c2 : c3;
    const int Kp    = (z == 0) ? 1024 : (z == 1) ? 256 : (z == 2) ? 64 : 32;
    const short* pb = (z == 0) ? pb0 : (z == 1) ? pb1 : (z == 2) ? pb2 : pb3;
    const int    P2 = (z == 0) ? 2048 : (z == 1) ? 2048 : (z == 2) ? 16384 : 8192;
    const long   EB = (z == 0) ? 0 : (z == 1) ? 262144 : (z == 2) ? 327680 : 458752;
    const int nt   = Kp >> 5;               // 32 / 8 / 2 / 1
    const int row0 = yb * 64, col0 = xb * 256;
    const int* list = lists + (size_t)z * n;

    // [buf][kgroup][row|col] 16B units; 8 + 32 KiB = 40 KiB total
    __shared__ __align__(16) short e_s[2 * 2048];
    __shared__ __align__(16) short p_s[2 * 8192];

    const int tid = threadIdx.x;
    const int wave = tid >> 6, lane = tid & 63;
    const int lm = lane & 15, quad = lane >> 4;

    // E staging: wave w = kgroup w; lane l -> compacted row (clamped)
    int er = row0 + lane; const int rc = count - 1; if (er > rc) er = rc;
    const short* esrc = ec + (size_t)(EB + (long)wave * P2 + er) * 8;
    const size_t eStep = (size_t)P2 * 32;   // 4 kgroups * P2 chunks * 8 shorts
    // P staging: wave w = kgroup w; 4 contiguous 1KB issues (64 cols each)
    const short* ps0 = pb + (size_t)(wave * 1024 + col0 +       lane) * 8;
    const short* ps1 = pb + (size_t)(wave * 1024 + col0 +  64 + lane) * 8;
    const short* ps2 = pb + (size_t)(wave * 1024 + col0 + 128 + lane) * 8;
    const short* ps3 = pb + (size_t)(wave * 1024 + col0 + 192 + lane) * 8;
    const size_t pStep = (size_t)4 * 1024 * 8;

    f32x4 acc[4][4];    // [a = 16-col group][b = 16-row group]
    #pragma unroll
    for (int a = 0; a < 4; ++a)
        #pragma unroll
        for (int b = 0; b < 4; ++b) acc[a][b] = (f32x4){0.f, 0.f, 0.f, 0.f};

    // prologue: stage step 0 into buf 0 (5 gll16 per wave)
    gll16(esrc, e_s + wave * 512);
    gll16(ps0,  p_s + wave * 2048);
    gll16(ps1,  p_s + wave * 2048 + 512);
    gll16(ps2,  p_s + wave * 2048 + 1024);
    gll16(ps3,  p_s + wave * 2048 + 1536);

    for (int t = 0; t < nt; ++t) {
        const int cur = t & 1;
        if (t + 1 < nt) {
            const size_t eo = (size_t)(t + 1) * eStep;
            const size_t po = (size_t)(t + 1) * pStep;
            const int nb = cur ^ 1;
            gll16(esrc + eo, e_s + nb * 2048 + wave * 512);
            gll16(ps0  + po, p_s + nb * 8192 + wave * 2048);
            gll16(ps1  + po, p_s + nb * 8192 + wave * 2048 + 512);
            gll16(ps2  + po, p_s + nb * 8192 + wave * 2048 + 1024);
            gll16(ps3  + po, p_s + nb * 8192 + wave * 2048 + 1536);
            // own cur-step writes done (oldest 5); next 5 stay in flight
            asm volatile("s_waitcnt vmcnt(5)" ::: "memory");
        } else {
            asm volatile("s_waitcnt vmcnt(0)" ::: "memory");
        }
        __builtin_amdgcn_s_barrier();           // all waves' cur writes visible
        __builtin_amdgcn_sched_barrier(0);

        const short* eb = e_s + cur * 2048 + quad * 512 + lm * 8;
        const short* pa = p_s + cur * 8192 + quad * 2048 + wave * 512 + lm * 8;
        bf16x8 B0 = *(const bf16x8*)(eb);
        bf16x8 B1 = *(const bf16x8*)(eb + 128);
        bf16x8 B2 = *(const bf16x8*)(eb + 256);
        bf16x8 B3 = *(const bf16x8*)(eb + 384);
        bf16x8 A0 = *(const bf16x8*)(pa);
        bf16x8 A1 = *(const bf16x8*)(pa + 128);
        bf16x8 A2 = *(const bf16x8*)(pa + 256);
        bf16x8 A3 = *(const bf16x8*)(pa + 384);

        acc[0][0] = __builtin_amdgcn_mfma_f32_16x16x32_bf16(A0, B0, acc[0][0], 0, 0, 0);
        acc[1][0] = __builtin_amdgcn_mfma_f32_16x16x32_bf16(A1, B0, acc[1][0], 0, 0, 0);
        acc[2][0] = __builtin_amdgcn_mfma_f32_16x16x32_bf16(A2, B0, acc[2][0], 0, 0, 0);
        acc[3][0] = __builtin_amdgcn_mfma_f32_16x16x32_bf16(A3, B0, acc[3][0], 0, 0, 0);
        acc[0][1] = __builtin_amdgcn_mfma_f32_16x16x32_bf16(A0, B1, acc[0][1], 0, 0, 0);
        acc[1][1] = __builtin_amdgcn_mfma_f32_16x16x32_bf16(A1, B1, acc[1][1], 0, 0, 0);
        acc[2][1] = __builtin_amdgcn_mfma_f32_16x16x32_bf16(A2, B1, acc[2][1], 0, 0, 0);
        acc[3][1] = __builtin_amdgcn_mfma_f32_16x16x32_bf16(A3, B1, acc[3][1], 0, 0, 0);
        acc[0][2] = __builtin_amdgcn_mfma_f32_16x16x32_bf16(A0, B2, acc[0][2], 0, 0, 0);
        acc[1][2] = __builtin_amdgcn_mfma_f32_16x16x32_bf16(A1, B2, acc[1][2], 0, 0, 0);
        acc[2][2] = __builtin_amdgcn_mfma_f32_16x16x32_bf16(A2, B2, acc[2][2], 0, 0, 0);
        acc[3][2] = __builtin_amdgcn_mfma_f32_16x16x32_bf16(A3, B2, acc[3][2], 0, 0, 0);
        acc[0][3] = __builtin_amdgcn_mfma_f32_16x16x32_bf16(A0, B3, acc[0][3], 0, 0, 0);
        acc[1][3] = __builtin_amdgcn_mfma_f32_16x16x32_bf16(A1, B3, acc[1][3], 0, 0, 0);
        acc[2][3] = __builtin_amdgcn_mfma_f32_16x16x32_bf16(A2, B3, acc[2][3], 0, 0, 0);
        acc[3][3] = __builtin_amdgcn_mfma_f32_16x16x32_bf16(A3, B3, acc[3][3], 0, 0, 0);

        if (t + 1 < nt) {
            // WAR: own ds_reads done, then barrier so no wave overwrites a
            // buffer others still read.
            asm volatile("s_waitcnt lgkmcnt(0)" ::: "memory");
            __builtin_amdgcn_sched_barrier(0);
            __builtin_amdgcn_s_barrier();
            __builtin_amdgcn_sched_barrier(0);
        }
    }

    // epilogue: D row = proj col (quad*4+reg), D col = token (lm)
    const int colW = col0 + wave * 64 + quad * 4;
    #pragma unroll
    for (int b = 0; b < 4; ++b) {
        const int r = row0 + b * 16 + lm;
        if (r < count) {
            const int tok = (int)((unsigned)list[r] >> 18);
            float* orow = out + (size_t)tok * DPROJ + colW;
            #pragma unroll
            for (int a = 0; a < 4; ++a)
                *(f32x4*)(orow + a * 16) = acc[a][b] * 32.f;
        }
    }
}

extern "C" void kernel_launch(void* const* d_in, const int* in_sizes, int n_in,
                              void* d_out, int out_size, void* d_ws, size_t ws_size,
                              hipStream_t stream) {
    const int*   inp = (const int*)d_in[0];
    const float* e0  = (const float*)d_in[1];
    const float* p0  = (const float*)d_in[2];
    const float* e1  = (const float*)d_in[3];
    const float* p1  = (const float*)d_in[4];
    const float* e2  = (const float*)d_in[5];
    const float* p2  = (const float*)d_in[6];
    const float* e3  = (const float*)d_in[7];
    const float* p3  = (const float*)d_in[8];
    float* out = (float*)d_out;
    const int n = in_sizes[0];  // 16384 tokens

    // ws: cnt[4] pad | lists[4n] | pb0..pb3 (k-major) | ec (k-major, ~7.5MB)
    char* wsb  = (char*)d_ws;
    int* cnt   = (int*)wsb;
    int* lists = (int*)(wsb + 32);
    size_t off = 32 + (size_t)4 * n * sizeof(int);
    off = (off + 255) & ~(size_t)255;
    short* pb0 = (short*)(wsb + off); off += (size_t)131072 * 16;
    short* pb1 = (short*)(wsb + off); off += (size_t)32768 * 16;
    short* pb2 = (short*)(wsb + off); off += (size_t)8192 * 16;
    short* pb3 = (short*)(wsb + off); off += (size_t)4096 * 16;
    short* ec  = (short*)(wsb + off); off += (size_t)491520 * 16;

    hipMemsetAsync(cnt, 0, 32, stream);

    const int CB = (n + 255) >> 8;
    k_prep<<<CB + 688, 256, 0, stream>>>(inp, n, cnt, lists,
                                         p0, p1, p2, p3, pb0, pb1, pb2, pb3);
    k_egather<<<1920, 256, 0, stream>>>(cnt, lists, n, e0, e1, e2, e3, ec);

    // exact tile grid: sum ceil(c_z/64) <= n/64 + 4 y-tiles, 4 col-panels each
    const int NT = (n + 63) / 64 + 4;
    k_gemm<<<NT * 4, 256, 0, stream>>>(cnt, lists, n, ec,
                                       pb0, pb1, pb2, pb3, out);
}